// Round 5
// baseline (522.089 us; speedup 1.0000x reference)
//
#include <hip/hip_runtime.h>
#include <math.h>

// GatedSpikingReservoirStep — fp16-single MFMA fused kernel + fp64 fixup.
// Round 11: rounds 7-10 (4 different schedules: drain-per-step, counted
// vmcnt depth 1/3, BK 32/64) ALL land at MfmaUtil~11%, ~253us. Per-step time
// is 4.7k cy while prefetch issues loads 3 steps (~14k cy) ahead -> the paid
// latency is NOT load arrival; it's the per-step cross-wave s_barrier convoy
// (only 2 independent wave-groups/CU). This matches m102: m97-structure at
// N=2048 ceilings at 320 TF; we sit at 271.
// Fix: wave-private staging -> ZERO barriers in the kernel. Each wave stages
// its own 64xBK A- and B-slabs into private LDS (2 bufs x 8KB; 64KB/block)
// and reads only its own region. 8 independent streams/CU, counted vmcnt(8)
// per wave, asm ds_read (no compiler drains). A/B staged 2x per block
// (~2.1GB aggregate, L2-served; 34TB/s L2 -> ~60us floor). Same r0-verified
// swizzle (0 conflicts), same MFMA fragments, identical fp32 epilogue.

#define IDIM 512
#define DDIM 2048
#define MAXD 2560
#define BDIM 4096
#define LIST_CAP 262144
#define BAND 4e-3f

typedef __attribute__((ext_vector_type(4))) float f32x4;
typedef __attribute__((ext_vector_type(8))) _Float16 f16x8;

__device__ __forceinline__ void gld16(const unsigned short* g, unsigned short* l) {
    __builtin_amdgcn_global_load_lds((const __attribute__((address_space(1))) void*)g,
                                     (__attribute__((address_space(3))) void*)l,
                                     16, 0, 0);
}
__device__ __forceinline__ f16x8 dsr(unsigned off) {
    f16x8 r;
    asm volatile("ds_read_b128 %0, %1" : "=v"(r) : "v"(off));
    return r;
}
__device__ __forceinline__ float sigf(float x) { return 1.0f / (1.0f + __expf(-x)); }

// ---------------------------------------------------------------------------
// convert: fp32 -> fp16 for X, S=state[:, :2048], Wc=[Win;Wgate], Wr;
// zero out-pad; zero fixup counter. 20480 blocks x 256 (float4 units).
// ---------------------------------------------------------------------------
__global__ __launch_bounds__(256) void convert_kernel(
    const float* __restrict__ x, const float* __restrict__ state,
    const float* __restrict__ win, const float* __restrict__ wgate,
    const float* __restrict__ wres,
    unsigned short* __restrict__ X16, unsigned short* __restrict__ S16,
    unsigned short* __restrict__ Wc16, unsigned short* __restrict__ Wr16,
    float* __restrict__ out, unsigned* __restrict__ cnt)
{
    int idx = blockIdx.x * 256 + threadIdx.x;
    if (idx == 0) *cnt = 0u;
    float4 v;
    unsigned short* p;
    long off;
    if (idx < 524288) {
        v = ((const float4*)x)[idx];
        p = X16; off = (long)idx * 4;
    } else if (idx < 2621440) {
        int i = idx - 524288;
        int row = i >> 9, c4 = i & 511;
        v = *(const float4*)(state + (long)row * MAXD + c4 * 4);
        p = S16; off = (long)i * 4;
    } else if (idx < 3670016) {
        int i = idx - 2621440;
        v = (i < 262144) ? ((const float4*)win)[i] : ((const float4*)wgate)[i - 262144];
        p = Wc16; off = (long)i * 4;
    } else if (idx < 4718592) {
        int i = idx - 3670016;
        v = ((const float4*)wres)[i];
        p = Wr16; off = (long)i * 4;
    } else {
        int i = idx - 4718592;
        int row = i >> 7, c4 = i & 127;
        *(float4*)(out + (long)row * MAXD + DDIM + c4 * 4) = make_float4(0.f, 0.f, 0.f, 0.f);
        return;
    }
    _Float16 h0 = (_Float16)v.x, h1 = (_Float16)v.y;
    _Float16 h2 = (_Float16)v.z, h3 = (_Float16)v.w;
    ushort4 hv;
    hv.x = *(unsigned short*)&h0; hv.y = *(unsigned short*)&h1;
    hv.z = *(unsigned short*)&h2; hv.w = *(unsigned short*)&h3;
    *(ushort4*)(p + off) = hv;
}

// ---------------------------------------------------------------------------
// fused_step: 5 GEMM phases (virtual K=4096) + gating epilogue, 128x128 tile.
// 4 waves x 64x64 quadrant, acc[4][4], BK=32. BARRIER-FREE: wave-private LDS
// (per wave: 2 buffers x (A 64x32 + B 64x32) hw = 16 KiB). Per step per wave:
// 8 gld16 (stage s+1) -> vmcnt(8) -> 8 asm ds_read_b128 -> lgkmcnt(0) ->
// 16 MFMA. Swizzle: write chunk=(lane&3)^((lane>>3)&3) via global src,
// read chunk=quad^((l16>>1)&3)  (r0 geometry, measured 0 bank conflicts).
// ---------------------------------------------------------------------------
__global__ __launch_bounds__(256, 2) void fused_step(
    const unsigned short* __restrict__ X16, const unsigned short* __restrict__ S16,
    const unsigned short* __restrict__ Wc16, const unsigned short* __restrict__ Wr16,
    const float* __restrict__ state, float* __restrict__ out,
    unsigned* __restrict__ cnt, unsigned* __restrict__ list)
{
    __shared__ alignas(16) unsigned short ldsm[32768];   // 64 KiB = 4 waves x 16 KiB
    const int t = threadIdx.x;
    const int wave = t >> 6, lane = t & 63;
    const int wr = wave >> 1, wc = wave & 1;
    const int quad = lane >> 4, l16 = lane & 15;
    const int m0 = blockIdx.y * 128;
    const int n0 = blockIdx.x * 128;
    // staging geometry: each gld16 covers 16 rows x 32k; lane -> (row, chunk)
    const int srow = lane >> 2;                           // 0..15
    const int kg = ((lane & 3) ^ ((lane >> 3) & 3)) * 8;  // write-side chunk (hw)
    // read-side swizzled chunk (bytes)
    const unsigned krb = (unsigned)((quad ^ ((l16 >> 1) & 3)) << 4);

    const unsigned LB = (unsigned)(unsigned long)(__attribute__((address_space(3))) unsigned short*)ldsm;
    const unsigned wbase = LB + (unsigned)(wave * 16384); // private 16 KiB
    const unsigned rrow = (unsigned)(l16 * 64) + krb;     // within-slab row offset

    f32x4 acc[4][4];
    f32x4 u[4][4];    // sum -> 0.2*tanh(i*sum) -> + 0.8*f*prev  (2 live sets)

    #pragma unroll
    for (int mi = 0; mi < 4; mi++)
        #pragma unroll
        for (int ni = 0; ni < 4; ni++)
            acc[mi][ni] = (f32x4)0.0f;

    auto phase = [&](const unsigned short* Ag, long ldA,
                     const unsigned short* Bg, long ldB, int klen) {
        const int nsteps = klen >> 5;                     // BK=32
        // this wave's private global slabs
        const unsigned short* aS = Ag + (long)(wr * 64 + srow) * ldA + kg;
        const unsigned short* bS = Bg + (long)(wc * 64 + srow) * ldB + kg;

        auto stage = [&](int s) {
            unsigned short* dA = ldsm + wave * 8192 + (s & 1) * 4096;  // halfwords
            unsigned short* dB = dA + 2048;
            const long k0 = (long)s << 5;
            #pragma unroll
            for (int j = 0; j < 4; j++) {
                gld16(aS + k0 + (long)(j * 16) * ldA, dA + j * 512);
                gld16(bS + k0 + (long)(j * 16) * ldB, dB + j * 512);
            }
        };

        stage(0);
        #pragma unroll 2
        for (int s = 0; s < nsteps; s++) {
            if (s + 1 < nsteps) {
                stage(s + 1);
                asm volatile("s_waitcnt vmcnt(8)" ::: "memory");  // s landed; s+1 in flight
            } else {
                asm volatile("s_waitcnt vmcnt(0)" ::: "memory");
            }
            const unsigned ab = wbase + (unsigned)((s & 1) * 8192);
            f16x8 af[4], bf[4];
            #pragma unroll
            for (int mi = 0; mi < 4; mi++) af[mi] = dsr(ab + mi * 1024 + rrow);
            #pragma unroll
            for (int ni = 0; ni < 4; ni++) bf[ni] = dsr(ab + 4096 + ni * 1024 + rrow);
            asm volatile("s_waitcnt lgkmcnt(0)" ::: "memory");
            __builtin_amdgcn_sched_barrier(0);
            #pragma unroll
            for (int mi = 0; mi < 4; mi++)
                #pragma unroll
                for (int ni = 0; ni < 4; ni++)
                    acc[mi][ni] = __builtin_amdgcn_mfma_f32_16x16x32_f16(af[mi], bf[ni], acc[mi][ni], 0, 0, 0);
        }
    };

    // Phase 0: acc = prev @ Wres^T          (K = 2048)
    phase(S16 + (long)m0 * DDIM, DDIM, Wr16 + (long)n0 * DDIM, DDIM, DDIM);
    // Phase 1: acc += X @ Win^T  -> u = ip + rp   (K = 512)
    phase(X16 + (long)m0 * IDIM, IDIM, Wc16 + (long)n0 * IDIM, IDIM, IDIM);
    #pragma unroll
    for (int mi = 0; mi < 4; mi++)
        #pragma unroll
        for (int ni = 0; ni < 4; ni++) { u[mi][ni] = acc[mi][ni]; acc[mi][ni] = (f32x4)0.0f; }

    // Phase 2: acc = X @ Wg_i^T  -> u = 0.2*tanh(sig(acc)*u)
    phase(X16 + (long)m0 * IDIM, IDIM, Wc16 + (long)(DDIM + n0) * IDIM, IDIM, IDIM);
    #pragma unroll
    for (int mi = 0; mi < 4; mi++)
        #pragma unroll
        for (int ni = 0; ni < 4; ni++) {
            #pragma unroll
            for (int r = 0; r < 4; r++)
                u[mi][ni][r] = 0.2f * tanhf(sigf(acc[mi][ni][r]) * u[mi][ni][r]);
            acc[mi][ni] = (f32x4)0.0f;
        }

    // Phase 3: acc = X @ Wg_f^T  -> u += 0.8*sig(acc)*prev
    phase(X16 + (long)m0 * IDIM, IDIM, Wc16 + (long)(2 * DDIM + n0) * IDIM, IDIM, IDIM);
    #pragma unroll
    for (int mi = 0; mi < 4; mi++)
        #pragma unroll
        for (int ni = 0; ni < 4; ni++) {
            #pragma unroll
            for (int r = 0; r < 4; r++) {
                int row = m0 + wr * 64 + mi * 16 + quad * 4 + r;
                int col = n0 + wc * 64 + ni * 16 + l16;
                float prev = state[(long)row * MAXD + col];
                u[mi][ni][r] += 0.8f * sigf(acc[mi][ni][r]) * prev;
            }
            acc[mi][ni] = (f32x4)0.0f;
        }

    // Phase 4: acc = X @ Wg_o^T  -> ns = sig(acc)*u -> spike -> write
    phase(X16 + (long)m0 * IDIM, IDIM, Wc16 + (long)(3 * DDIM + n0) * IDIM, IDIM, IDIM);
    #pragma unroll
    for (int mi = 0; mi < 4; mi++)
        #pragma unroll
        for (int ni = 0; ni < 4; ni++) {
            #pragma unroll
            for (int r = 0; r < 4; r++) {
                int row = m0 + wr * 64 + mi * 16 + quad * 4 + r;
                int col = n0 + wc * 64 + ni * 16 + l16;
                float go = sigf(acc[mi][ni][r]);
                float ns = go * u[mi][ni][r];
                float ov = (ns > 0.5f) ? ns - 0.5f : ns;
                out[(long)row * MAXD + col] = ov;
                if (fabsf(ns - 0.5f) < BAND) {
                    unsigned pos = atomicAdd(cnt, 1u);
                    if (pos < LIST_CAP) list[pos] = (unsigned)(row * DDIM + col);
                }
            }
        }
}

// ---------------------------------------------------------------------------
// fixup: recompute flagged elements exactly in fp64, float4-vectorized loads.
// ---------------------------------------------------------------------------
__global__ __launch_bounds__(256) void fixup_kernel(
    const float* __restrict__ x, const float* __restrict__ state,
    const float* __restrict__ win, const float* __restrict__ wres,
    const float* __restrict__ wgate,
    const unsigned* __restrict__ cnt, const unsigned* __restrict__ list,
    float* __restrict__ out)
{
    const int gwave = (blockIdx.x * 256 + threadIdx.x) >> 6;
    const int lane = threadIdx.x & 63;
    const int nwaves = gridDim.x * 4;
    unsigned n = *cnt;
    if (n > LIST_CAP) n = LIST_CAP;
    for (unsigned e = gwave; e < n; e += nwaves) {
        unsigned rc = list[e];
        int row = rc >> 11, col = rc & 2047;
        double ip = 0.0, gi = 0.0, gf = 0.0, go = 0.0, rp = 0.0;
        const float* xr  = x + (long)row * IDIM;
        const float* wi  = win + (long)col * IDIM;
        const float* wgi = wgate + (long)col * IDIM;
        const float* wgf = wgate + (long)(DDIM + col) * IDIM;
        const float* wgo = wgate + (long)(2 * DDIM + col) * IDIM;
        #pragma unroll
        for (int k = lane * 4; k < IDIM; k += 256) {
            float4 xv = *(const float4*)(xr + k);
            float4 a = *(const float4*)(wi + k);
            float4 b = *(const float4*)(wgi + k);
            float4 c = *(const float4*)(wgf + k);
            float4 d = *(const float4*)(wgo + k);
            ip += (double)xv.x * a.x + (double)xv.y * a.y + (double)xv.z * a.z + (double)xv.w * a.w;
            gi += (double)xv.x * b.x + (double)xv.y * b.y + (double)xv.z * b.z + (double)xv.w * b.w;
            gf += (double)xv.x * c.x + (double)xv.y * c.y + (double)xv.z * c.z + (double)xv.w * c.w;
            go += (double)xv.x * d.x + (double)xv.y * d.y + (double)xv.z * d.z + (double)xv.w * d.w;
        }
        const float* sr = state + (long)row * MAXD;
        const float* wr_ = wres + (long)col * DDIM;
        #pragma unroll 2
        for (int k = lane * 4; k < DDIM; k += 256) {
            float4 sv = *(const float4*)(sr + k);
            float4 wv = *(const float4*)(wr_ + k);
            rp += (double)sv.x * wv.x + (double)sv.y * wv.y + (double)sv.z * wv.z + (double)sv.w * wv.w;
        }
        #pragma unroll
        for (int o = 32; o > 0; o >>= 1) {
            ip += __shfl_down(ip, o);
            gi += __shfl_down(gi, o);
            gf += __shfl_down(gf, o);
            go += __shfl_down(go, o);
            rp += __shfl_down(rp, o);
        }
        if (lane == 0) {
            double si = 1.0 / (1.0 + exp(-gi));
            double sf = 1.0 / (1.0 + exp(-gf));
            double so = 1.0 / (1.0 + exp(-go));
            double prev = (double)state[(long)row * MAXD + col];
            double ns = so * (0.8 * sf * prev + 0.2 * tanh(si * (ip + rp)));
            if (ns > 0.5) ns -= 0.5;
            out[(long)row * MAXD + col] = (float)ns;
        }
    }
}

extern "C" void kernel_launch(void* const* d_in, const int* in_sizes, int n_in,
                              void* d_out, int out_size, void* d_ws, size_t ws_size,
                              hipStream_t stream) {
    const float* x     = (const float*)d_in[0];   // (4096, 512)
    const float* state = (const float*)d_in[1];   // (4096, 2560)
    const float* win   = (const float*)d_in[2];   // (2048, 512)
    const float* wres  = (const float*)d_in[3];   // (2048, 2048)
    const float* wgate = (const float*)d_in[4];   // (6144, 512)
    float* out = (float*)d_out;

    char* ws = (char*)d_ws;
    unsigned short* X16  = (unsigned short*)(ws);                   //  0.. 4 MiB
    unsigned short* S16  = (unsigned short*)(ws + (4ll  << 20));    //  4..20
    unsigned short* Wc16 = (unsigned short*)(ws + (20ll << 20));    // 20..28
    unsigned short* Wr16 = (unsigned short*)(ws + (28ll << 20));    // 28..36
    unsigned* cnt  = (unsigned*)(ws + (36ll << 20));                // 4 B
    unsigned* list = (unsigned*)(ws + (36ll << 20) + 16);           // 1 MiB

    convert_kernel<<<dim3(20480), dim3(256), 0, stream>>>(
        x, state, win, wgate, wres, X16, S16, Wc16, Wr16, out, cnt);

    fused_step<<<dim3(16, 32), dim3(256), 0, stream>>>(
        X16, S16, Wc16, Wr16, state, out, cnt, list);

    fixup_kernel<<<dim3(1024), dim3(256), 0, stream>>>(
        x, state, win, wres, wgate, cnt, list, out);
}

// Round 6
// 400.207 us; speedup vs baseline: 1.3045x; 1.3045x over previous
//
#include <hip/hip_runtime.h>
#include <math.h>

// GatedSpikingReservoirStep — fp16-single MFMA fused kernel + fp64 fixup.
// Round 12: OCCUPANCY, not scheduling. r0-r5 (5 schedules incl. barrier-free)
// all pinned at OccupancyPercent 21-25% = 8 waves/CU = 2 blocks/CU, because
// the unified VGPR+AGPR budget (VGPR_Count 84-128 + 96-128 accumulator AGPRs
// = 180-256 total) lands every variant in the 2-waves/SIMD residency bin.
// At 8 waves/CU the in-order staging path can't cover L2/HBM latency ->
// identical ~250us regardless of schedule (r5: time scales with staged
// bytes). Fix: tile 128x64, wave owns 64x32 -> acc[4][2]+u[4][2] = 64 acc
// regs (half of r1); __launch_bounds__(256,4) forces total <=128 so 4
// waves/SIMD fit; grid 32x32 = 1024 blocks = 4 blocks/CU; LDS 12KB
// single-buffered. Structure = r1's simple sync/gld/sync/read-mfma (m97's:
// at 16 waves/CU cross-block overlap hides the drain). Same r0-verified
// swizzle, identical fp32 epilogue algebra -> absmax unchanged.

#define IDIM 512
#define DDIM 2048
#define MAXD 2560
#define BDIM 4096
#define LIST_CAP 262144
#define BAND 4e-3f

typedef __attribute__((ext_vector_type(4))) float f32x4;
typedef __attribute__((ext_vector_type(8))) _Float16 f16x8;

__device__ __forceinline__ void gld16(const unsigned short* g, unsigned short* l) {
    __builtin_amdgcn_global_load_lds((const __attribute__((address_space(1))) void*)g,
                                     (__attribute__((address_space(3))) void*)l,
                                     16, 0, 0);
}
__device__ __forceinline__ float sigf(float x) { return 1.0f / (1.0f + __expf(-x)); }

// ---------------------------------------------------------------------------
// convert: fp32 -> fp16 for X, S=state[:, :2048], Wc=[Win;Wgate], Wr;
// zero out-pad; zero fixup counter. 20480 blocks x 256 (float4 units).
// ---------------------------------------------------------------------------
__global__ __launch_bounds__(256) void convert_kernel(
    const float* __restrict__ x, const float* __restrict__ state,
    const float* __restrict__ win, const float* __restrict__ wgate,
    const float* __restrict__ wres,
    unsigned short* __restrict__ X16, unsigned short* __restrict__ S16,
    unsigned short* __restrict__ Wc16, unsigned short* __restrict__ Wr16,
    float* __restrict__ out, unsigned* __restrict__ cnt)
{
    int idx = blockIdx.x * 256 + threadIdx.x;
    if (idx == 0) *cnt = 0u;
    float4 v;
    unsigned short* p;
    long off;
    if (idx < 524288) {
        v = ((const float4*)x)[idx];
        p = X16; off = (long)idx * 4;
    } else if (idx < 2621440) {
        int i = idx - 524288;
        int row = i >> 9, c4 = i & 511;
        v = *(const float4*)(state + (long)row * MAXD + c4 * 4);
        p = S16; off = (long)i * 4;
    } else if (idx < 3670016) {
        int i = idx - 2621440;
        v = (i < 262144) ? ((const float4*)win)[i] : ((const float4*)wgate)[i - 262144];
        p = Wc16; off = (long)i * 4;
    } else if (idx < 4718592) {
        int i = idx - 3670016;
        v = ((const float4*)wres)[i];
        p = Wr16; off = (long)i * 4;
    } else {
        int i = idx - 4718592;
        int row = i >> 7, c4 = i & 127;
        *(float4*)(out + (long)row * MAXD + DDIM + c4 * 4) = make_float4(0.f, 0.f, 0.f, 0.f);
        return;
    }
    _Float16 h0 = (_Float16)v.x, h1 = (_Float16)v.y;
    _Float16 h2 = (_Float16)v.z, h3 = (_Float16)v.w;
    ushort4 hv;
    hv.x = *(unsigned short*)&h0; hv.y = *(unsigned short*)&h1;
    hv.z = *(unsigned short*)&h2; hv.w = *(unsigned short*)&h3;
    *(ushort4*)(p + off) = hv;
}

// ---------------------------------------------------------------------------
// fused_step: 5 GEMM phases (virtual K=4096) + gating epilogue, 128x64 tile.
// 4 waves, each owns a 64x32 sub-tile (wr = M-half, wc = N-half), acc[4][2],
// BK=32, LDS 12KB single-buffered. Per step per wave: 3 gld16 + 6 LDS frag
// reads + 8 MFMA. r0's measured-conflict-free chunk-XOR swizzle.
// ---------------------------------------------------------------------------
__global__ __launch_bounds__(256, 4) void fused_step(
    const unsigned short* __restrict__ X16, const unsigned short* __restrict__ S16,
    const unsigned short* __restrict__ Wc16, const unsigned short* __restrict__ Wr16,
    const float* __restrict__ state, float* __restrict__ out,
    unsigned* __restrict__ cnt, unsigned* __restrict__ list)
{
    __shared__ alignas(16) unsigned short lA[128 * 32];
    __shared__ alignas(16) unsigned short lB[64 * 32];
    const int t = threadIdx.x;
    const int wave = t >> 6, lane = t & 63;
    const int wr = wave >> 1, wc = wave & 1;
    const int quad = lane >> 4, l16 = lane & 15;
    const int m0 = blockIdx.y * 128;
    const int n0 = blockIdx.x * 64;
    const int rowoff = lane >> 2;                         // 0..15
    const int kg = ((lane & 3) ^ ((lane >> 3) & 3)) * 8;  // swizzled global k-chunk
    const int kr = (quad ^ ((l16 >> 1) & 3)) * 8;         // swizzled LDS read k

    f32x4 acc[4][2];
    f32x4 u[4][2];    // sum -> 0.2*tanh(i*sum) -> + 0.8*f*prev  (2 live sets)

    #pragma unroll
    for (int mi = 0; mi < 4; mi++)
        #pragma unroll
        for (int ni = 0; ni < 2; ni++)
            acc[mi][ni] = (f32x4)0.0f;

    auto phase = [&](const unsigned short* Ag, long ldA,
                     const unsigned short* Bg, long ldB, int klen) {
        const unsigned short* a0 = Ag + (long)(wave * 32 + rowoff) * ldA + kg;
        const unsigned short* a1 = a0 + (long)16 * ldA;
        const unsigned short* b0 = Bg + (long)(wave * 16 + rowoff) * ldB + kg;
        unsigned short* dA = lA + wave * 1024;
        unsigned short* dB = lB + wave * 512;
        for (int k0 = 0; k0 < klen; k0 += 32) {
            __syncthreads();
            gld16(a0 + k0, dA);
            gld16(a1 + k0, dA + 512);
            gld16(b0 + k0, dB);
            __syncthreads();
            f16x8 af[4], bf[2];
            #pragma unroll
            for (int mi = 0; mi < 4; mi++)
                af[mi] = *(const f16x8*)&lA[(wr * 64 + mi * 16 + l16) * 32 + kr];
            #pragma unroll
            for (int ni = 0; ni < 2; ni++)
                bf[ni] = *(const f16x8*)&lB[(wc * 32 + ni * 16 + l16) * 32 + kr];
            #pragma unroll
            for (int mi = 0; mi < 4; mi++)
                #pragma unroll
                for (int ni = 0; ni < 2; ni++)
                    acc[mi][ni] = __builtin_amdgcn_mfma_f32_16x16x32_f16(af[mi], bf[ni], acc[mi][ni], 0, 0, 0);
        }
    };

    // Phase 0: acc = prev @ Wres^T          (K = 2048)
    phase(S16 + (long)m0 * DDIM, DDIM, Wr16 + (long)n0 * DDIM, DDIM, DDIM);
    // Phase 1: acc += X @ Win^T  -> u = ip + rp   (K = 512)
    phase(X16 + (long)m0 * IDIM, IDIM, Wc16 + (long)n0 * IDIM, IDIM, IDIM);
    #pragma unroll
    for (int mi = 0; mi < 4; mi++)
        #pragma unroll
        for (int ni = 0; ni < 2; ni++) { u[mi][ni] = acc[mi][ni]; acc[mi][ni] = (f32x4)0.0f; }

    // Phase 2: acc = X @ Wg_i^T  -> u = 0.2*tanh(sig(acc)*u)
    phase(X16 + (long)m0 * IDIM, IDIM, Wc16 + (long)(DDIM + n0) * IDIM, IDIM, IDIM);
    #pragma unroll
    for (int mi = 0; mi < 4; mi++)
        #pragma unroll
        for (int ni = 0; ni < 2; ni++) {
            #pragma unroll
            for (int r = 0; r < 4; r++)
                u[mi][ni][r] = 0.2f * tanhf(sigf(acc[mi][ni][r]) * u[mi][ni][r]);
            acc[mi][ni] = (f32x4)0.0f;
        }

    // Phase 3: acc = X @ Wg_f^T  -> u += 0.8*sig(acc)*prev
    phase(X16 + (long)m0 * IDIM, IDIM, Wc16 + (long)(2 * DDIM + n0) * IDIM, IDIM, IDIM);
    #pragma unroll
    for (int mi = 0; mi < 4; mi++)
        #pragma unroll
        for (int ni = 0; ni < 2; ni++) {
            #pragma unroll
            for (int r = 0; r < 4; r++) {
                int row = m0 + wr * 64 + mi * 16 + quad * 4 + r;
                int col = n0 + wc * 32 + ni * 16 + l16;
                float prev = state[(long)row * MAXD + col];
                u[mi][ni][r] += 0.8f * sigf(acc[mi][ni][r]) * prev;
            }
            acc[mi][ni] = (f32x4)0.0f;
        }

    // Phase 4: acc = X @ Wg_o^T  -> ns = sig(acc)*u -> spike -> write
    phase(X16 + (long)m0 * IDIM, IDIM, Wc16 + (long)(3 * DDIM + n0) * IDIM, IDIM, IDIM);
    #pragma unroll
    for (int mi = 0; mi < 4; mi++)
        #pragma unroll
        for (int ni = 0; ni < 2; ni++) {
            #pragma unroll
            for (int r = 0; r < 4; r++) {
                int row = m0 + wr * 64 + mi * 16 + quad * 4 + r;
                int col = n0 + wc * 32 + ni * 16 + l16;
                float go = sigf(acc[mi][ni][r]);
                float ns = go * u[mi][ni][r];
                float ov = (ns > 0.5f) ? ns - 0.5f : ns;
                out[(long)row * MAXD + col] = ov;
                if (fabsf(ns - 0.5f) < BAND) {
                    unsigned pos = atomicAdd(cnt, 1u);
                    if (pos < LIST_CAP) list[pos] = (unsigned)(row * DDIM + col);
                }
            }
        }
}

// ---------------------------------------------------------------------------
// fixup: recompute flagged elements exactly in fp64, float4-vectorized loads.
// ---------------------------------------------------------------------------
__global__ __launch_bounds__(256) void fixup_kernel(
    const float* __restrict__ x, const float* __restrict__ state,
    const float* __restrict__ win, const float* __restrict__ wres,
    const float* __restrict__ wgate,
    const unsigned* __restrict__ cnt, const unsigned* __restrict__ list,
    float* __restrict__ out)
{
    const int gwave = (blockIdx.x * 256 + threadIdx.x) >> 6;
    const int lane = threadIdx.x & 63;
    const int nwaves = gridDim.x * 4;
    unsigned n = *cnt;
    if (n > LIST_CAP) n = LIST_CAP;
    for (unsigned e = gwave; e < n; e += nwaves) {
        unsigned rc = list[e];
        int row = rc >> 11, col = rc & 2047;
        double ip = 0.0, gi = 0.0, gf = 0.0, go = 0.0, rp = 0.0;
        const float* xr  = x + (long)row * IDIM;
        const float* wi  = win + (long)col * IDIM;
        const float* wgi = wgate + (long)col * IDIM;
        const float* wgf = wgate + (long)(DDIM + col) * IDIM;
        const float* wgo = wgate + (long)(2 * DDIM + col) * IDIM;
        #pragma unroll
        for (int k = lane * 4; k < IDIM; k += 256) {
            float4 xv = *(const float4*)(xr + k);
            float4 a = *(const float4*)(wi + k);
            float4 b = *(const float4*)(wgi + k);
            float4 c = *(const float4*)(wgf + k);
            float4 d = *(const float4*)(wgo + k);
            ip += (double)xv.x * a.x + (double)xv.y * a.y + (double)xv.z * a.z + (double)xv.w * a.w;
            gi += (double)xv.x * b.x + (double)xv.y * b.y + (double)xv.z * b.z + (double)xv.w * b.w;
            gf += (double)xv.x * c.x + (double)xv.y * c.y + (double)xv.z * c.z + (double)xv.w * c.w;
            go += (double)xv.x * d.x + (double)xv.y * d.y + (double)xv.z * d.z + (double)xv.w * d.w;
        }
        const float* sr = state + (long)row * MAXD;
        const float* wr_ = wres + (long)col * DDIM;
        #pragma unroll 2
        for (int k = lane * 4; k < DDIM; k += 256) {
            float4 sv = *(const float4*)(sr + k);
            float4 wv = *(const float4*)(wr_ + k);
            rp += (double)sv.x * wv.x + (double)sv.y * wv.y + (double)sv.z * wv.z + (double)sv.w * wv.w;
        }
        #pragma unroll
        for (int o = 32; o > 0; o >>= 1) {
            ip += __shfl_down(ip, o);
            gi += __shfl_down(gi, o);
            gf += __shfl_down(gf, o);
            go += __shfl_down(go, o);
            rp += __shfl_down(rp, o);
        }
        if (lane == 0) {
            double si = 1.0 / (1.0 + exp(-gi));
            double sf = 1.0 / (1.0 + exp(-gf));
            double so = 1.0 / (1.0 + exp(-go));
            double prev = (double)state[(long)row * MAXD + col];
            double ns = so * (0.8 * sf * prev + 0.2 * tanh(si * (ip + rp)));
            if (ns > 0.5) ns -= 0.5;
            out[(long)row * MAXD + col] = (float)ns;
        }
    }
}

extern "C" void kernel_launch(void* const* d_in, const int* in_sizes, int n_in,
                              void* d_out, int out_size, void* d_ws, size_t ws_size,
                              hipStream_t stream) {
    const float* x     = (const float*)d_in[0];   // (4096, 512)
    const float* state = (const float*)d_in[1];   // (4096, 2560)
    const float* win   = (const float*)d_in[2];   // (2048, 512)
    const float* wres  = (const float*)d_in[3];   // (2048, 2048)
    const float* wgate = (const float*)d_in[4];   // (6144, 512)
    float* out = (float*)d_out;

    char* ws = (char*)d_ws;
    unsigned short* X16  = (unsigned short*)(ws);                   //  0.. 4 MiB
    unsigned short* S16  = (unsigned short*)(ws + (4ll  << 20));    //  4..20
    unsigned short* Wc16 = (unsigned short*)(ws + (20ll << 20));    // 20..28
    unsigned short* Wr16 = (unsigned short*)(ws + (28ll << 20));    // 28..36
    unsigned* cnt  = (unsigned*)(ws + (36ll << 20));                // 4 B
    unsigned* list = (unsigned*)(ws + (36ll << 20) + 16);           // 1 MiB

    convert_kernel<<<dim3(20480), dim3(256), 0, stream>>>(
        x, state, win, wgate, wres, X16, S16, Wc16, Wr16, out, cnt);

    fused_step<<<dim3(32, 32), dim3(256), 0, stream>>>(
        X16, S16, Wc16, Wr16, state, out, cnt, list);

    fixup_kernel<<<dim3(1024), dim3(256), 0, stream>>>(
        x, state, win, wres, wgate, cnt, list, out);
}